// Round 2
// baseline (497.036 us; speedup 1.0000x reference)
//
#include <hip/hip_runtime.h>
#include <math.h>
#include <cstddef>

#define T_SAMP 256000
#define TFRM   4001
#define NF     257
#define NB     40
#define NBATCH 32
#define OFFOUT ((size_t)NBATCH*NB*TFRM)
#define TWO_PI 6.283185307179586f

typedef _Float16 f16;

#define MV_ELEMS   ((size_t)NBATCH * TFRM * NF)          // 32,904,224 halfs
#define STATE_N    (8 * NBATCH * NF)                      // 65,792 channels
#define STATE_BYTES ((size_t)STATE_N * 8)                 // float2
#define NEED_BYTES (STATE_BYTES + MV_ELEMS * 2)           // 66,334,784

static __device__ __forceinline__ float sigmoidf_(float x) { return 1.f/(1.f+expf(-x)); }

// ---------------------------------------------------------------------------
// K1: STFT magnitude -> fp16 mv[b][t][f]. 16 frames/block, 16 threads/frame.
// 512-pt rFFT: pack 256 complex, 16x16 four-step FFT, rfft untangle.
// Output staged in LDS per block, then linear coalesced copy-out.
// ---------------------------------------------------------------------------
__global__ __launch_bounds__(256) void k1_stft(const float* __restrict__ vib,
                                               const float* __restrict__ window,
                                               f16* __restrict__ mv) {
  __shared__ float4 xs4[368];            // 1472 floats input span
  __shared__ float2 win2[256];
  __shared__ float2 w16s[16];
  __shared__ float2 w256[256];
  __shared__ float  w512c[257];
  __shared__ float  w512s[257];
  __shared__ float2 Hst[16][16][16];     // [frame][c][r^c]; aliased as Z after
  __shared__ f16    lmag[16 * 257];

  float*  xsf = (float*)xs4;
  float2 (*Zb)[256] = (float2(*)[256])Hst;

  const int tid = threadIdx.x;
  const int b   = blockIdx.x;
  const int t0  = blockIdx.y * 16;

  {
    win2[tid] = ((const float2*)window)[tid];
    float sv, cv;
    sincosf(TWO_PI * (float)tid * (1.f/256.f), &sv, &cv);
    w256[tid] = make_float2(cv, -sv);
    if (tid < 16) {
      float s2, c2;
      sincosf(TWO_PI * (float)tid * (1.f/16.f), &s2, &c2);
      w16s[tid] = make_float2(c2, -s2);
    }
    for (int i = tid; i < 257; i += 256) {
      float s3, c3;
      sincosf(TWO_PI * (float)i * (1.f/512.f), &s3, &c3);
      w512c[i] = c3; w512s[i] = s3;
    }
  }

  // load input span with reflect padding
  const int s0 = t0 * 64 - 256;
  for (int i = tid; i < 1472; i += 256) {
    int m = s0 + i;
    m = (m < 0) ? -m : m;
    if (m >= T_SAMP) m = 2*(T_SAMP-1) - m;
    xsf[i] = vib[(size_t)b * T_SAMP + m];
  }
  __syncthreads();

  const int fl = tid >> 4;
  const int r  = tid & 15;
  const int t  = t0 + fl;

  float2 z[16];
  const float2* xz = (const float2*)(xsf + fl * 64);
  #pragma unroll
  for (int a = 0; a < 16; ++a) {
    float2 xv = xz[r + 16*a];
    float2 wv = win2[r + 16*a];
    z[a] = make_float2(xv.x * wv.x, xv.y * wv.y);
  }
  float2 wr[16];
  #pragma unroll
  for (int j = 0; j < 16; ++j) wr[j] = w16s[j];

  // stage A
  #pragma unroll
  for (int c = 0; c < 16; ++c) {
    float2 acc = z[0];
    #pragma unroll
    for (int a = 1; a < 16; ++a) {
      float2 w = wr[(a*c) & 15];
      acc.x = fmaf(w.x, z[a].x, fmaf(-w.y, z[a].y, acc.x));
      acc.y = fmaf(w.x, z[a].y, fmaf( w.y, z[a].x, acc.y));
    }
    float2 tw = w256[(r*c) & 255];
    float2 h;
    h.x = acc.x*tw.x - acc.y*tw.y;
    h.y = acc.x*tw.y + acc.y*tw.x;
    Hst[fl][c][r ^ c] = h;
  }
  __syncthreads();

  // stage B
  float2 hv[16];
  #pragma unroll
  for (int q = 0; q < 16; ++q) hv[q] = Hst[fl][r][q ^ r];
  __syncthreads();
  float2 Zv[16];
  #pragma unroll
  for (int d = 0; d < 16; ++d) {
    float2 acc = hv[0];
    #pragma unroll
    for (int q = 1; q < 16; ++q) {
      float2 w = wr[(q*d) & 15];
      acc.x = fmaf(w.x, hv[q].x, fmaf(-w.y, hv[q].y, acc.x));
      acc.y = fmaf(w.x, hv[q].y, fmaf( w.y, hv[q].x, acc.y));
    }
    Zv[d] = acc;
  }
  #pragma unroll
  for (int d = 0; d < 16; ++d) Zb[fl][r + 16*d] = Zv[d];
  __syncthreads();

  // stage C: rfft untangle + |X| -> LDS (fp16)
  if (t < TFRM) {
    #pragma unroll
    for (int j = 0; j < 17; ++j) {
      int k = r + 16*j;
      if (j == 16) { if (r != 0) break; k = 256; }
      float2 A  = Zb[fl][k & 255];
      float2 Bv = Zb[fl][(256 - k) & 255];
      float Er = 0.5f*(A.x + Bv.x), Ei = 0.5f*(A.y - Bv.y);
      float Dr = 0.5f*(A.x - Bv.x), Di = 0.5f*(A.y + Bv.y);
      float tc = w512c[k], ts = w512s[k];
      float Xr = Er + tc*Di - ts*Dr;
      float Xi = Ei - tc*Dr - ts*Di;
      lmag[fl * 257 + k] = (f16)sqrtf(Xr*Xr + Xi*Xi);
    }
  }
  __syncthreads();

  // linear coalesced copy-out of the block's contiguous [t0, t0+nv) rows
  const int nv = (TFRM - t0 < 16) ? (TFRM - t0) : 16;
  f16* dst = mv + ((size_t)b * TFRM + t0) * NF;
  for (int i = tid; i < nv * 257; i += 256) dst[i] = lmag[i];
}

// ---------------------------------------------------------------------------
// K2a: warm-up pass (read-only). 8 chunks x 8224 channels.
// Saves {nf_at_chunk_start, floor_min} so K2b can run in place race-free.
// Contraction: (1-fall)^384 ~ 8e-9 -> warm-up state error below fp16 noise.
// ---------------------------------------------------------------------------
__global__ __launch_bounds__(256) void k2_warm(const f16* __restrict__ mv,
                                               float2* __restrict__ state,
                                               const float* __restrict__ rrp,
                                               const float* __restrict__ rfp) {
  const int gid   = blockIdx.x * 256 + threadIdx.x;   // 257*256 = 65792
  const int chunk = gid / 8224;
  const int ch    = gid - chunk * 8224;
  const int b     = ch / NF;
  const int f     = ch - b * NF;

  const float rise = sigmoidf_(rrp[0]);
  const float fall = sigmoidf_(rfp[0]);

  const f16* mp = mv + (size_t)b * TFRM * NF + f;

  float mn = 3.4e38f;
  #pragma unroll
  for (int tq = 0; tq < 20; ++tq) mn = fminf(mn, (float)mp[tq * NF]);
  const float initm  = fmaxf(mn, 1e-5f);
  const float floorm = 0.5f * initm;

  const int t0 = chunk * 512;
  const int ts = (chunk == 0) ? 0 : (t0 - 384);

  float nf = initm;
  const f16* rp = mp + (size_t)ts * NF;
  #pragma unroll 4
  for (int t = ts; t < t0; ++t) {
    float m = (float)*rp; rp += NF;
    float a = (m > nf) ? rise : fall;
    nf = fmaxf(fmaf(a, m - nf, nf), floorm);
  }
  state[gid] = make_float2(nf, floorm);
}

// ---------------------------------------------------------------------------
// K2b: main scan, overwrites mag with vnr IN PLACE (each thread touches only
// its own [t0,t1) strictly read-then-write; warm-up done in K2a launch).
// ---------------------------------------------------------------------------
__global__ __launch_bounds__(256) void k2_main(f16* __restrict__ mv,
                                               const float2* __restrict__ state,
                                               const float* __restrict__ nscp,
                                               const float* __restrict__ rrp,
                                               const float* __restrict__ rfp) {
  const int gid   = blockIdx.x * 256 + threadIdx.x;
  const int chunk = gid / 8224;
  const int ch    = gid - chunk * 8224;
  const int b     = ch / NF;
  const int f     = ch - b * NF;

  const float rise  = sigmoidf_(rrp[0]);
  const float fall  = sigmoidf_(rfp[0]);
  const float scale = fabsf(nscp[0]);

  const float2 st   = state[gid];
  float nf          = st.x;
  const float floorm = st.y;

  const int t0 = chunk * 512;
  const int t1 = (t0 + 512 < TFRM) ? (t0 + 512) : TFRM;

  f16* p = mv + (size_t)b * TFRM * NF + f + (size_t)t0 * NF;
  #pragma unroll 4
  for (int t = t0; t < t1; ++t) {
    float m = (float)*p;
    float a = (m > nf) ? rise : fall;
    nf = fmaxf(fmaf(a, m - nf, nf), floorm);
    float v = m / fmaf(scale, nf, 1e-8f);
    v = fminf(v, 30000.f);              // fp16-safe; tanh(v/10) saturated anyway
    *p = (f16)v;
    p += NF;
  }
}

// ---------------------------------------------------------------------------
// K3: sparse band projection of mv. MODE 0: dst = fb@mv (band of mag).
// MODE 1: dst = tanh(fb@mv / 10) (vnr bands). 256 t/block, 16-f LDS chunks.
// ---------------------------------------------------------------------------
template<int MODE>
__global__ __launch_bounds__(256) void k3_proj(const f16* __restrict__ mv,
                                               const float* __restrict__ fb,
                                               float* __restrict__ dst) {
  __shared__ float fbl[NB * NF];        // 41120 B
  __shared__ int   sr[NB], er[NB];
  __shared__ f16   tile[256][18];       // 9216 B (pad 2)

  const int tid = threadIdx.x;
  const int b   = blockIdx.x;
  const int t0  = blockIdx.y * 256;

  for (int i = tid; i < NB * NF; i += 256) fbl[i] = fb[i];
  __syncthreads();
  if (tid < NB) {
    int s = NF, e = 0;
    for (int f2 = 0; f2 < NF; ++f2)
      if (fbl[tid * NF + f2] > 0.f) { if (f2 < s) s = f2; e = f2 + 1; }
    sr[tid] = s; er[tid] = e;
  }

  const int t = t0 + tid;
  float acc[NB];
  #pragma unroll
  for (int n = 0; n < NB; ++n) acc[n] = 0.f;

  for (int fc = 0; fc < NF; fc += 16) {
    __syncthreads();
    {
      const int row = tid >> 4, col = tid & 15;
      #pragma unroll
      for (int kq = 0; kq < 16; ++kq) {
        const int rrow = row + kq * 16;
        const int ff   = (fc + col < NF) ? (fc + col) : (NF - 1);
        const int tt   = (t0 + rrow < TFRM) ? (t0 + rrow) : (TFRM - 1);
        tile[rrow][col] = mv[((size_t)b * TFRM + tt) * NF + ff];
      }
    }
    __syncthreads();
    const int ce = (fc + 16 < NF) ? (fc + 16) : NF;
    #pragma unroll
    for (int n = 0; n < NB; ++n) {
      const int lo = max(sr[n], fc), hi = min(er[n], ce);
      for (int f2 = lo; f2 < hi; ++f2)
        acc[n] = fmaf(fbl[n * NF + f2], (float)tile[tid][f2 - fc], acc[n]);
    }
  }

  if (t < TFRM) {
    #pragma unroll
    for (int n = 0; n < NB; ++n) {
      const size_t o = (size_t)(b * NB + n) * TFRM + t;
      dst[o] = (MODE == 0) ? acc[n] : tanhf(acc[n] * 0.1f);
    }
  }
}

// ---------------------------------------------------------------------------
// K4: kurtosis gate + per-row standardize. Block per (b,band); row held in
// registers (read fully before in-place write). No __restrict__: band==feat.
// ---------------------------------------------------------------------------
__device__ __forceinline__ float blk_sum(float v, float* scr) {
  #pragma unroll
  for (int o = 32; o > 0; o >>= 1) v += __shfl_down(v, o, 64);
  const int lane = threadIdx.x & 63, w = threadIdx.x >> 6;
  __syncthreads();
  if (lane == 0) scr[w] = v;
  __syncthreads();
  return scr[0] + scr[1] + scr[2] + scr[3];
}

__global__ __launch_bounds__(256) void k4_gate(const float* band,
                                               const float* vnrb,
                                               const float* gw,
                                               const float* gb,
                                               const float* gf,
                                               float* feat) {
  __shared__ float scr[4];
  const int bid = blockIdx.x;
  const int b = bid / NB, n = bid - b * NB;
  const size_t base = (size_t)(b * NB + n) * TFRM;
  const float* row = band + base;
  const float* vr  = vnrb + base;
  const int tid = threadIdx.x;

  float xl[16];
  float s1 = 0.f;
  #pragma unroll
  for (int q = 0; q < 16; ++q) {
    int i = tid + q * 256;
    xl[q] = (i < TFRM) ? row[i] : 0.f;
    s1 += xl[q];
  }
  s1 = blk_sum(s1, scr);
  const float mu = s1 * (1.f / 4001.f);

  float s2 = 0.f, s4 = 0.f;
  #pragma unroll
  for (int q = 0; q < 16; ++q) {
    int i = tid + q * 256;
    if (i < TFRM) { float d = xl[q] - mu; float d2 = d * d; s2 += d2; s4 += d2 * d2; }
  }
  s2 = blk_sum(s2, scr);
  s4 = blk_sum(s4, scr);
  const float var  = fmaxf(s2 * (1.f / 4001.f), 1e-8f);
  const float kurt = (s4 * (1.f / 4001.f)) / (var * var + 1e-8f);
  const float kn   = (kurt - 3.f) * (1.f / 3.f);

  const float fl = sigmoidf_(gf[n]);
  float g0 = sigmoidf_(fmaf(gw[n], kn, gb[n]));
  g0 = g0 * (1.f - fl) + fl;

  float sy = 0.f;
  #pragma unroll
  for (int q = 0; q < 16; ++q) {
    int i = tid + q * 256;
    if (i < TFRM) {
      float y = xl[q] * g0 * (0.5f + 0.5f * vr[i]);
      xl[q] = y; sy += y;
    } else xl[q] = 0.f;
  }
  sy = blk_sum(sy, scr);
  const float mean = sy * (1.f / 4001.f);

  float sv = 0.f;
  #pragma unroll
  for (int q = 0; q < 16; ++q) {
    int i = tid + q * 256;
    if (i < TFRM) { float d = xl[q] - mean; sv += d * d; }
  }
  sv = blk_sum(sv, scr);
  const float rstd = 1.f / sqrtf(sv * (1.f / 4001.f) + 1e-5f);

  #pragma unroll
  for (int q = 0; q < 16; ++q) {
    int i = tid + q * 256;
    if (i < TFRM) feat[base + i] = (xl[q] - mean) * rstd;
  }
}

// ---------------------------------------------------------------------------
extern "C" void kernel_launch(void* const* d_in, const int* in_sizes, int n_in,
                              void* d_out, int out_size, void* d_ws, size_t ws_size,
                              hipStream_t stream) {
  const float* vib = (const float*)d_in[0];
  const float* fb  = (const float*)d_in[1];
  const float* win = (const float*)d_in[2];
  const float* nsc = (const float*)d_in[3];
  const float* rr  = (const float*)d_in[4];
  const float* rf  = (const float*)d_in[5];
  const float* gw  = (const float*)d_in[6];
  const float* gb  = (const float*)d_in[7];
  const float* gf  = (const float*)d_in[8];
  float* out = (float*)d_out;
  (void)in_sizes; (void)n_in; (void)out_size;

  if (ws_size < NEED_BYTES) return;   // diagnostic clean-fail instead of fault

  float2* state = (float2*)d_ws;
  f16*    mv    = (f16*)((char*)d_ws + STATE_BYTES);

  hipLaunchKernelGGL(k1_stft,    dim3(32, 251), dim3(256), 0, stream, vib, win, mv);
  hipLaunchKernelGGL(k2_warm,    dim3(257),     dim3(256), 0, stream, mv, state, rr, rf);
  hipLaunchKernelGGL(k3_proj<0>, dim3(32, 16),  dim3(256), 0, stream, mv, fb, out);
  hipLaunchKernelGGL(k2_main,    dim3(257),     dim3(256), 0, stream, mv, state, nsc, rr, rf);
  hipLaunchKernelGGL(k3_proj<1>, dim3(32, 16),  dim3(256), 0, stream, mv, fb, out + OFFOUT);
  hipLaunchKernelGGL(k4_gate,    dim3(1280),    dim3(256), 0, stream,
                     out, out + OFFOUT, gw, gb, gf, out);
}